// Round 5
// baseline (2370.672 us; speedup 1.0000x reference)
//
#include <hip/hip_runtime.h>
#include <hip/hip_cooperative_groups.h>
#include <math.h>

namespace cg = cooperative_groups;

typedef _Float16 f16;
typedef _Float16 f16x8 __attribute__((ext_vector_type(8)));
typedef float f32x4 __attribute__((ext_vector_type(4)));

#define NB 16      // batch
#define NT 16      // time steps
#define NH 64
#define NW 64
#define NF 64      // features
#define NG 256     // 4*F
#define HWF ((size_t)NH * NW * NF)          // 262144
#define OUT_BSTRIDE ((size_t)NT * HWF)      // d_out batch stride
#define RS 16896                            // LDS row stride = 66 * 256 B (x-padded)

#define MFMA(a, b, c) __builtin_amdgcn_mfma_f32_16x16x32_f16((a), (b), (c), 0, 0, 0)

__device__ __forceinline__ void gload_lds16(const void* g, void* l) {
    __builtin_amdgcn_global_load_lds(
        (const __attribute__((address_space(1))) unsigned int*)(g),
        (__attribute__((address_space(3))) unsigned int*)(l), 16, 0, 0);
}

__device__ __forceinline__ float hsig(float x) {
    return fminf(fmaxf(0.2f * x + 0.5f, 0.0f), 1.0f);
}

// ---- prologue 1: fuse W+U, split fp16 hi/lo, layout [t*9+tap][cout][hi(64)|lo(64)]
__global__ void fuse_split_w(const float* __restrict__ k, const float* __restrict__ rk,
                             f16* __restrict__ wf2) {
    int idx = blockIdx.x * 256 + threadIdx.x;      // over 16*9*256*64
    if (idx >= NT * 9 * NG * NF) return;
    int cin  = idx & 63;
    int cout = (idx >> 6) & 255;
    int tt   = idx >> 14;                          // t*9 + tap
    size_t src = ((size_t)tt * NF + cin) * NG + cout;
    float w = k[src] + rk[src];
    f16 hi = (f16)w;
    size_t dst = ((size_t)tt * NG + cout) * 128 + cin;
    wf2[dst]      = hi;
    wf2[dst + 64] = (f16)(w - (float)hi);
}

// ---- prologue 2: split h0 to fp16 hi/lo, layout [b][y][x][hi(64)|lo(64)]
__global__ void split_h(const float* __restrict__ h0, f16* __restrict__ h2) {
    int idx = blockIdx.x * 256 + threadIdx.x;      // over 16*64*64*64
    if (idx >= (int)(NB * HWF)) return;
    int f = idx & 63;
    size_t p = (size_t)(idx >> 6);
    float v = h0[idx];
    f16 hi = (f16)v;
    h2[p * 128 + f]      = hi;
    h2[p * 128 + 64 + f] = (f16)(v - (float)hi);
}

// ================= shared per-step device code =================
// Block tile: 128 positions (2 image rows) x 256 couts, 8 waves (2m x 4n).
// LDS h tile: [4 rows][sx 0..65][hi128|lo128], x-padded; swizzle slot = k16 ^ (sx&7).

__device__ __forceinline__ void step_body(
    const f16* __restrict__ h2in, f16* __restrict__ h2out,
    const float* __restrict__ cprev, float* __restrict__ cnew,
    float* __restrict__ hout, const f16* __restrict__ wt,
    const float* __restrict__ bias,
    unsigned char* lds, int tid, int bb, int y0)
{
    const int w    = tid >> 6;
    const int lane = tid & 63;

    // zero the pad columns sx=0 and sx=65 (4 rows x 2 x 256B)
    if (tid < 128) {
        int row = tid >> 5, side = (tid >> 4) & 1, j = tid & 15;
        *(f16x8*)&lds[row * RS + side * (65 * 256) + j * 16] = (f16x8)(_Float16)0.0f;
    }

    // stage rows y0-1 .. y0+2 with pre-swizzled global source (rule 21)
    {
        const int r    = w >> 1;               // tile row 0..3
        const int gy   = y0 - 1 + r;
        const int half = w & 1;
        const unsigned dbase = r * RS + 256 + half * 8192;   // wave-uniform
        if (gy >= 0 && gy < NH) {
            const unsigned char* gsrc = (const unsigned char*)h2in +
                ((((size_t)bb * NH + gy) * NW) << 8);        // 256 B per (y,x)
            const int j = lane & 15;
#pragma unroll
            for (int i = 0; i < 8; ++i) {
                const int xrel = half * 32 + i * 4 + (lane >> 4);
                const unsigned src = ((unsigned)xrel << 8) +
                                     ((unsigned)(j ^ ((xrel + 1) & 7)) << 4);
                gload_lds16(gsrc + src, (void*)&lds[dbase + i * 1024]);
            }
        } else {
            const f16x8 zf = (f16x8)(_Float16)0.0f;
#pragma unroll
            for (int i = 0; i < 8; ++i)
                *(f16x8*)&lds[dbase + i * 1024 + lane * 16] = zf;
        }
    }
    __syncthreads();

    // ---------- K loop: 9 taps x 2 cin-halves, fully unrolled, 3-term split MFMA
    const int wm = w >> 2;
    const int wn = w & 3;
    const int lm = lane & 15;
    const int lg = lane >> 4;

    f32x4 acc[4][4];
#pragma unroll
    for (int mf = 0; mf < 4; ++mf)
#pragma unroll
        for (int nf = 0; nf < 4; ++nf) acc[mf][nf] = (f32x4)0.0f;

    unsigned av[3][2];
#pragma unroll
    for (int d = 0; d < 3; ++d)
#pragma unroll
        for (int kk = 0; kk < 2; ++kk) {
            const int sxl = lm + d;
            av[d][kk] = (unsigned)(sxl * 256 +
                        ((kk * 64 + lg * 16) ^ ((sxl & 7) << 4)));
        }

    const f16x8* wbn = (const f16x8*)wt + ((size_t)(wn * 64 + lm) * 16 + lg);

    f16x8 bh[4], bl[4];

#pragma unroll
    for (int it = 0; it < 18; ++it) {
        const int tap = it >> 1, kk = it & 1;
#pragma unroll
        for (int nf = 0; nf < 4; ++nf) {
            const f16x8* p = wbn + (tap * 4096 + nf * 256 + kk * 4);
            bh[nf] = p[0];
            bl[nf] = p[8];
        }
        const int ty = tap / 3;
        const int d  = tap - ty * 3;
        const unsigned abase = (unsigned)((wm + ty) * RS) + av[d][kk];
        __builtin_amdgcn_s_setprio(1);
        // term-major per mf: dependent same-acc MFMAs are 4 issues apart
#pragma unroll
        for (int mf = 0; mf < 4; ++mf) {
            const f16x8 ah = *(const f16x8*)&lds[abase + mf * 4096];
            const f16x8 al = *(const f16x8*)&lds[abase + mf * 4096 + 128];
#pragma unroll
            for (int nf = 0; nf < 4; ++nf)
                acc[mf][nf] = MFMA(ah, bh[nf], acc[mf][nf]);
#pragma unroll
            for (int nf = 0; nf < 4; ++nf)
                acc[mf][nf] = MFMA(al, bh[nf], acc[mf][nf]);
#pragma unroll
            for (int nf = 0; nf < 4; ++nf)
                acc[mf][nf] = MFMA(ah, bl[nf], acc[mf][nf]);
        }
        __builtin_amdgcn_s_setprio(0);
    }

    __syncthreads();

    // ---------- epilogue: z-exchange through LDS, fused LSTM pointwise
    float* zbuf = (float*)lds;
    const int f = tid & 63;
    const float bi = bias[f], bfv = bias[64 + f], bcv = bias[128 + f], bov = bias[192 + f];

#pragma unroll 1
    for (int half = 0; half < 2; ++half) {
        if (wm == half) {
#pragma unroll
            for (int mf = 0; mf < 4; ++mf)
#pragma unroll
                for (int nf = 0; nf < 4; ++nf)
#pragma unroll
                    for (int j = 0; j < 4; ++j)
                        zbuf[(mf * 16 + lg * 4 + j) * 256 + wn * 64 + nf * 16 + lm] =
                            acc[mf][nf][j];
        }
        __syncthreads();
        const int gy = y0 + half;
#pragma unroll 1
        for (int k2 = 0; k2 < 8; ++k2) {
            const int x = (tid >> 6) + k2 * 8;          // 0..63 (wave-uniform)
            const float* zz = zbuf + x * 256;
            float zi  = zz[f]       + bi;
            float zfv = zz[64 + f]  + bfv;
            float zc  = zz[128 + f] + bcv;
            float zo  = zz[192 + f] + bov;
            size_t goff = (((size_t)bb * NH + gy) * NW + x) * NF + f;
            float cp = cprev[goff];
            float ig = hsig(zi), fg = hsig(zfv), og = hsig(zo);
            float cn = fg * cp + ig * tanhf(zc);
            cnew[goff] = cn;
            float hn = og * tanhf(cn);
            hout[(size_t)bb * OUT_BSTRIDE + (((size_t)gy * NW + x) * NF + f)] = hn;
            size_t p2 = (((size_t)bb * NH + gy) * NW + x) * 128 + f;
            f16 hi = (f16)hn;
            h2out[p2]      = hi;
            h2out[p2 + 64] = (f16)(hn - (float)hi);
        }
        __syncthreads();
    }
}

// ================= fused persistent kernel (cooperative) =================
__global__ void __launch_bounds__(512, 4)
convlstm_fused(const f16* __restrict__ wf2,
               f16* __restrict__ h2a, f16* __restrict__ h2b,
               const float* __restrict__ c0, float* __restrict__ cbuf,
               float* __restrict__ out, const float* __restrict__ bias_all)
{
    cg::grid_group grid = cg::this_grid();
    __shared__ __align__(16) unsigned char lds[4 * RS];   // 67584 B

    const int tid = threadIdx.x;
    const int bb  = blockIdx.y;
    const int y0  = blockIdx.x * 2;

#pragma unroll 1
    for (int t = 0; t < NT; ++t) {
        const f16* h2in  = (t & 1) ? h2b : h2a;
        f16*       h2out = (t & 1) ? h2a : h2b;
        step_body(h2in, h2out,
                  (t == 0) ? c0 : cbuf, cbuf,
                  out + (size_t)t * HWF,
                  wf2 + (size_t)t * 9 * NG * 128,
                  bias_all + t * NG,
                  lds, tid, bb, y0);
        grid.sync();
    }
}

// ================= fallback: one step per launch =================
__global__ void __launch_bounds__(512, 4)
convlstm_mfma_step(const f16* __restrict__ h2in, f16* __restrict__ h2out,
                   const float* __restrict__ cprev, float* __restrict__ cnew,
                   float* __restrict__ hout, const f16* __restrict__ wt,
                   const float* __restrict__ bias)
{
    __shared__ __align__(16) unsigned char lds[4 * RS];
    step_body(h2in, h2out, cprev, cnew, hout, wt, bias,
              lds, threadIdx.x, blockIdx.y, blockIdx.x * 2);
}

extern "C" void kernel_launch(void* const* d_in, const int* in_sizes, int n_in,
                              void* d_out, int out_size, void* d_ws, size_t ws_size,
                              hipStream_t stream) {
    const float* h0    = (const float*)d_in[1];
    const float* c0    = (const float*)d_in[2];
    const float* kern  = (const float*)d_in[3];
    const float* rkern = (const float*)d_in[4];
    const float* bias  = (const float*)d_in[5];
    float* out = (float*)d_out;

    f16* wf2 = (f16*)d_ws;                                    // 9.4 MB
    f16* h2a = wf2 + (size_t)NT * 9 * NG * 128;               // 16.8 MB
    f16* h2b = h2a + (size_t)NB * NH * NW * 128;              // 16.8 MB
    float* cbuf = (float*)(h2b + (size_t)NB * NH * NW * 128); // 16.8 MB

    fuse_split_w<<<(NT * 9 * NG * NF + 255) / 256, 256, 0, stream>>>(kern, rkern, wf2);
    split_h<<<((int)(NB * HWF) + 255) / 256, 256, 0, stream>>>(h0, h2a);

    const f16* wf2c = wf2;
    const float* c0c = c0;
    const float* biasc = bias;
    void* args[] = { (void*)&wf2c, (void*)&h2a, (void*)&h2b,
                     (void*)&c0c, (void*)&cbuf, (void*)&out, (void*)&biasc };
    hipError_t ce = hipLaunchCooperativeKernel(
        (const void*)convlstm_fused, dim3(NH / 2, NB), dim3(512),
        args, 0u, stream);

    if (ce != hipSuccess) {
        (void)hipGetLastError();   // clear error state, use fallback path
        dim3 grid(NH / 2, NB);
        for (int t = 0; t < NT; ++t) {
            const f16* hin = (t & 1) ? h2b : h2a;
            f16* hnx       = (t & 1) ? h2a : h2b;
            convlstm_mfma_step<<<grid, 512, 0, stream>>>(
                hin, hnx,
                (t == 0) ? c0 : cbuf, cbuf,
                out + (size_t)t * HWF,
                wf2 + (size_t)t * 9 * NG * 128,
                bias + t * NG);
        }
    }
}

// Round 6
// 957.525 us; speedup vs baseline: 2.4758x; 2.4758x over previous
//
#include <hip/hip_runtime.h>
#include <math.h>

typedef _Float16 f16;
typedef _Float16 f16x8 __attribute__((ext_vector_type(8)));
typedef float f32x4 __attribute__((ext_vector_type(4)));

#define NB 16      // batch
#define NT 16      // time steps
#define NH 64
#define NW 64
#define NF 64      // features
#define NG 256     // 4*F
#define HWF ((size_t)NH * NW * NF)          // 262144
#define OUT_BSTRIDE ((size_t)NT * HWF)      // d_out batch stride
#define RS 16896                            // LDS row stride = 66 * 256 B (x-padded)
#define ZS 258                              // zbuf row stride in floats (bank-conflict-free)
#define WSTEP ((size_t)36864)               // per-step wf2 size in f16x8 chunks (= 294912 f16)

#define MFMA(a, b, c) __builtin_amdgcn_mfma_f32_16x16x32_f16((a), (b), (c), 0, 0, 0)

__device__ __forceinline__ void gload_lds16(const void* g, void* l) {
    __builtin_amdgcn_global_load_lds(
        (const __attribute__((address_space(1))) unsigned int*)(g),
        (__attribute__((address_space(3))) unsigned int*)(l), 16, 0, 0);
}

__device__ __forceinline__ float hsig(float x) {
    return fminf(fmaxf(0.2f * x + 0.5f, 0.0f), 1.0f);
}

// ---- prologue 1: fuse W+U, split fp16 hi/lo, repack LANE-ORDERED:
// chunk index (f16x8 units): (tap*2+kk)*2048 + term*1024 + (wn*4+nf)*64 + lane
// where lane = lg*16 + lm holds cout = block*16+lm, cin = kk*32 + lg*8 .. +7.
// A wave's B-fragment load is then base + lane*16B — fully coalesced.
__global__ void fuse_split_w(const float* __restrict__ k, const float* __restrict__ rk,
                             f16* __restrict__ wf2) {
    int idx = blockIdx.x * 256 + threadIdx.x;      // over 16*9*256*8 = 294912
    if (idx >= NT * 9 * NG * 8) return;
    int g8   = idx & 7;            // cin group of 8
    int cout = (idx >> 3) & 255;
    int tt   = idx >> 11;          // t*9 + tap
    int tap  = tt % 9;
    int t    = tt / 9;
    int kk = g8 >> 2, lg = g8 & 3;

    const float* ks = k  + (size_t)tt * NF * NG + cout;
    const float* rs = rk + (size_t)tt * NF * NG + cout;

    f16 hi8[8], lo8[8];
#pragma unroll
    for (int j = 0; j < 8; ++j) {
        int cin = kk * 32 + lg * 8 + j;
        float w = ks[(size_t)cin * NG] + rs[(size_t)cin * NG];
        f16 hi = (f16)w;
        hi8[j] = hi;
        lo8[j] = (f16)(w - (float)hi);
    }
    const int lane = lg * 16 + (cout & 15);
    size_t chunk = (size_t)t * WSTEP + (size_t)(tap * 2 + kk) * 2048 +
                   (size_t)(cout >> 4) * 64 + lane;
    *(f16x8*)&wf2[chunk * 8]        = *(f16x8*)hi8;   // term 0 (hi)
    *(f16x8*)&wf2[(chunk + 1024) * 8] = *(f16x8*)lo8; // term 1 (lo)
}

// ---- prologue 2: split h0 to fp16 hi/lo, layout [b][y][x][hi(64)|lo(64)]
__global__ void split_h(const float* __restrict__ h0, f16* __restrict__ h2) {
    int idx = blockIdx.x * 256 + threadIdx.x;      // over 16*64*64*64
    if (idx >= (int)(NB * HWF)) return;
    int f = idx & 63;
    size_t p = (size_t)(idx >> 6);
    float v = h0[idx];
    f16 hi = (f16)v;
    h2[p * 128 + f]      = hi;
    h2[p * 128 + 64 + f] = (f16)(v - (float)hi);
}

// ---- one ConvLSTM step via split-fp16 MFMA implicit conv.
// 512 threads = 8 waves (2 m x 4 n). Block tile: 128 positions (2 rows) x 256 couts.
__global__ void __launch_bounds__(512, 4)
convlstm_mfma_step(const f16* __restrict__ h2in, f16* __restrict__ h2out,
                   const float* __restrict__ cprev, float* __restrict__ cnew,
                   float* __restrict__ hout,        // d_out + t*HWF
                   const f16* __restrict__ wt,      // lane-ordered chunks for this t
                   const float* __restrict__ bias)  // [256] for this t
{
    __shared__ __align__(16) unsigned char lds[4 * RS];   // 67584 B

    const int tid  = threadIdx.x;
    const int w    = tid >> 6;
    const int lane = tid & 63;
    const int bb   = blockIdx.y;
    const int y0   = blockIdx.x * 2;

    // zero the pad columns sx=0 and sx=65 (4 rows x 2 x 256B)
    if (tid < 128) {
        int row = tid >> 5, side = (tid >> 4) & 1, j = tid & 15;
        *(f16x8*)&lds[row * RS + side * (65 * 256) + j * 16] = (f16x8)(_Float16)0.0f;
    }

    // stage rows y0-1 .. y0+2 with pre-swizzled global source (rule 21)
    {
        const int r    = w >> 1;               // tile row 0..3
        const int gy   = y0 - 1 + r;
        const int half = w & 1;
        const unsigned dbase = r * RS + 256 + half * 8192;   // wave-uniform
        if (gy >= 0 && gy < NH) {
            const unsigned char* gsrc = (const unsigned char*)h2in +
                ((((size_t)bb * NH + gy) * NW) << 8);        // 256 B per (y,x)
            const int j = lane & 15;
#pragma unroll
            for (int i = 0; i < 8; ++i) {
                const int xrel = half * 32 + i * 4 + (lane >> 4);
                const unsigned src = ((unsigned)xrel << 8) +
                                     ((unsigned)(j ^ ((xrel + 1) & 7)) << 4);
                gload_lds16(gsrc + src, (void*)&lds[dbase + i * 1024]);
            }
        } else {
            const f16x8 zf = (f16x8)(_Float16)0.0f;
#pragma unroll
            for (int i = 0; i < 8; ++i)
                *(f16x8*)&lds[dbase + i * 1024 + lane * 16] = zf;
        }
    }
    __syncthreads();

    // ---------- K loop: 9 taps x 2 cin-halves, fully unrolled, 3-term split MFMA
    const int wm = w >> 2;
    const int wn = w & 3;
    const int lm = lane & 15;
    const int lg = lane >> 4;

    f32x4 acc[4][4];
#pragma unroll
    for (int mf = 0; mf < 4; ++mf)
#pragma unroll
        for (int nf = 0; nf < 4; ++nf) acc[mf][nf] = (f32x4)0.0f;

    unsigned av[3][2];
#pragma unroll
    for (int d = 0; d < 3; ++d)
#pragma unroll
        for (int kk = 0; kk < 2; ++kk) {
            const int sxl = lm + d;
            av[d][kk] = (unsigned)(sxl * 256 +
                        ((kk * 64 + lg * 16) ^ ((sxl & 7) << 4)));
        }

    // coalesced B base: chunk (wn*4)*64 + lane
    const f16x8* wb = (const f16x8*)wt + (size_t)(wn * 4) * 64 + lane;

    f16x8 bh[4], bl[4];

#pragma unroll
    for (int it = 0; it < 18; ++it) {
        const int tap = it >> 1, kk = it & 1;
#pragma unroll
        for (int nf = 0; nf < 4; ++nf) {
            bh[nf] = wb[(size_t)it * 2048 + nf * 64];
            bl[nf] = wb[(size_t)it * 2048 + 1024 + nf * 64];
        }
        const int ty = tap / 3;
        const int d  = tap - ty * 3;
        const unsigned abase = (unsigned)((wm + ty) * RS) + av[d][kk];
        __builtin_amdgcn_s_setprio(1);
        // term-major per mf: dependent same-acc MFMAs are 4 issues apart
#pragma unroll
        for (int mf = 0; mf < 4; ++mf) {
            const f16x8 ah = *(const f16x8*)&lds[abase + mf * 4096];
            const f16x8 al = *(const f16x8*)&lds[abase + mf * 4096 + 128];
#pragma unroll
            for (int nf = 0; nf < 4; ++nf)
                acc[mf][nf] = MFMA(ah, bh[nf], acc[mf][nf]);
#pragma unroll
            for (int nf = 0; nf < 4; ++nf)
                acc[mf][nf] = MFMA(al, bh[nf], acc[mf][nf]);
#pragma unroll
            for (int nf = 0; nf < 4; ++nf)
                acc[mf][nf] = MFMA(ah, bl[nf], acc[mf][nf]);
        }
        __builtin_amdgcn_s_setprio(0);
    }

    __syncthreads();

    // ---------- epilogue: z-exchange through LDS (stride ZS=258: 2 lanes/bank, free),
    // fused LSTM pointwise.
    float* zbuf = (float*)lds;
    const int f = tid & 63;
    const float bi = bias[f], bfv = bias[64 + f], bcv = bias[128 + f], bov = bias[192 + f];

#pragma unroll 1
    for (int half = 0; half < 2; ++half) {
        if (wm == half) {
#pragma unroll
            for (int mf = 0; mf < 4; ++mf)
#pragma unroll
                for (int nf = 0; nf < 4; ++nf)
#pragma unroll
                    for (int j = 0; j < 4; ++j)
                        zbuf[(mf * 16 + lg * 4 + j) * ZS + wn * 64 + nf * 16 + lm] =
                            acc[mf][nf][j];
        }
        __syncthreads();
        const int gy = y0 + half;
#pragma unroll 1
        for (int k2 = 0; k2 < 8; ++k2) {
            const int x = (tid >> 6) + k2 * 8;          // 0..63 (wave-uniform)
            const float* zz = zbuf + x * ZS;
            float zi  = zz[f]       + bi;
            float zfv = zz[64 + f]  + bfv;
            float zc  = zz[128 + f] + bcv;
            float zo  = zz[192 + f] + bov;
            size_t goff = (((size_t)bb * NH + gy) * NW + x) * NF + f;
            float cp = cprev[goff];
            float ig = hsig(zi), fg = hsig(zfv), og = hsig(zo);
            float cn = fg * cp + ig * tanhf(zc);
            cnew[goff] = cn;
            float hn = og * tanhf(cn);
            hout[(size_t)bb * OUT_BSTRIDE + (((size_t)gy * NW + x) * NF + f)] = hn;
            size_t p2 = (((size_t)bb * NH + gy) * NW + x) * 128 + f;
            f16 hi = (f16)hn;
            h2out[p2]      = hi;
            h2out[p2 + 64] = (f16)(hn - (float)hi);
        }
        __syncthreads();
    }
}

extern "C" void kernel_launch(void* const* d_in, const int* in_sizes, int n_in,
                              void* d_out, int out_size, void* d_ws, size_t ws_size,
                              hipStream_t stream) {
    const float* h0    = (const float*)d_in[1];
    const float* c0    = (const float*)d_in[2];
    const float* kern  = (const float*)d_in[3];
    const float* rkern = (const float*)d_in[4];
    const float* bias  = (const float*)d_in[5];
    float* out = (float*)d_out;

    f16* wf2 = (f16*)d_ws;                                    // 9.4 MB
    f16* h2a = wf2 + (size_t)NT * WSTEP * 8;                  // 16.8 MB
    f16* h2b = h2a + (size_t)NB * NH * NW * 128;              // 16.8 MB
    float* cbuf = (float*)(h2b + (size_t)NB * NH * NW * 128); // 16.8 MB

    fuse_split_w<<<(NT * 9 * NG * 8 + 255) / 256, 256, 0, stream>>>(kern, rkern, wf2);
    split_h<<<((int)(NB * HWF) + 255) / 256, 256, 0, stream>>>(h0, h2a);

    dim3 grid(NH / 2, NB);
    for (int t = 0; t < NT; ++t) {
        const f16* hin = (t & 1) ? h2b : h2a;
        f16* hnx       = (t & 1) ? h2a : h2b;
        convlstm_mfma_step<<<grid, 512, 0, stream>>>(
            hin, hnx,
            (t == 0) ? c0 : cbuf, cbuf,
            out + (size_t)t * HWF,
            wf2 + (size_t)t * WSTEP * 8,
            bias + t * NG);
    }
}